// Round 1
// 357.726 us; speedup vs baseline: 1.0352x; 1.0352x over previous
//
#include <hip/hip_runtime.h>

#define L_SEQ 2048
#define BATCH 32
#define HID   1024
#define FLOAT_MIN -1e20f

typedef float f32x4 __attribute__((ext_vector_type(4)));

// ---------------------------------------------------------------------------
// Kernel 1: v[b,h] = sum_g hidden[b,g] * W[g,h];  c[b] = sum_g hidden[b,g]*bias[g]
// Grid: 256 blocks -> b = bid/8, n-tile(128 cols) = bid%8. 256 threads.
// W column-tile is re-read per b but stays L2/L3 resident (W = 4 MB total;
// block->XCD round-robin maps tile nt to XCD nt, so each XCD L2 holds 512 KB).
// ---------------------------------------------------------------------------
__global__ __launch_bounds__(256) void proj_kernel(
    const float* __restrict__ hidden,   // [B,H]
    const float* __restrict__ W,        // [H,H]  (g-major, h contiguous)
    const float* __restrict__ bias,     // [H]
    float* __restrict__ v,              // [B,H]
    float* __restrict__ c)              // [B]
{
    __shared__ float  sh_hidden[HID];
    __shared__ float4 sh_part[8][32];
    __shared__ float  sh_red[4];

    const int b  = blockIdx.x >> 3;
    const int nt = blockIdx.x & 7;
    const int t  = threadIdx.x;

    // stage hidden[b,:] (4 KB) into LDS
    ((float4*)sh_hidden)[t] = ((const float4*)(hidden + (size_t)b * HID))[t];
    __syncthreads();

    const int j4   = t & 31;    // float4 column within the 128-col tile
    const int half = t >> 5;    // 0..7 : k-partition of 128 rows each
    const int n0   = nt * 128;

    float4 acc = make_float4(0.f, 0.f, 0.f, 0.f);
    const int kbase = half * 128;
    #pragma unroll 4
    for (int k = kbase; k < kbase + 128; ++k) {
        const float  hg = sh_hidden[k];                          // LDS broadcast
        const float4 w  = ((const float4*)(W + (size_t)k * HID + n0))[j4];
        acc.x += hg * w.x; acc.y += hg * w.y;
        acc.z += hg * w.z; acc.w += hg * w.w;
    }
    sh_part[half][j4] = acc;
    __syncthreads();

    if (t < 32) {
        float4 s = sh_part[0][t];
        #pragma unroll
        for (int h = 1; h < 8; ++h) {
            const float4 p = sh_part[h][t];
            s.x += p.x; s.y += p.y; s.z += p.z; s.w += p.w;
        }
        ((float4*)(v + (size_t)b * HID + n0))[t] = s;
    }

    if (nt == 0) {  // block-uniform branch: compute c[b] once per b
        float p = 0.f;
        #pragma unroll
        for (int g = t; g < HID; g += 256) p += sh_hidden[g] * bias[g];
        #pragma unroll
        for (int off = 32; off > 0; off >>= 1) p += __shfl_down(p, off, 64);
        if ((t & 63) == 0) sh_red[t >> 6] = p;
        __syncthreads();
        if (t == 0) c[b] = sh_red[0] + sh_red[1] + sh_red[2] + sh_red[3];
    }
}

// ---------------------------------------------------------------------------
// Kernel 2: energies[b,l] = v[b] . enc[l,b,:] + c[b]   -- ONLY for l < len[b].
// FOUR rows per wave, 16 enc dwordx4 loads issued up-front (deep vmcnt queue),
// 4 independent shuffle-reduce chains.
//
// R6 change: enc is read with NON-TEMPORAL loads (nt bit). Rationale: the
// harness's 1 GiB workspace poison fill runs immediately before this kernel
// and leaves the 256 MiB L3 full of DIRTY lines. Cacheable enc reads force an
// eviction-writeback stream (~192 MB) that shares HBM with our 192 MB read
// stream -> the ~4.2 TB/s effective rate seen in R5. enc has zero reuse
// within an iteration, so L3 allocation buys nothing; nt loads skip retention
// and leave the dirty poison lines to be overwritten by the next fill.
// v / lengths / energies keep normal caching (real L2 reuse).
// ---------------------------------------------------------------------------
__global__ __launch_bounds__(256) void energy_kernel(
    const float* __restrict__ enc,      // [L,B,H] = [L*B rows][H]
    const float* __restrict__ v,        // [B,H]
    const float* __restrict__ c,        // [B]
    const int*   __restrict__ lengths,  // [B]
    float* __restrict__ energies)       // [B,L]
{
    const int t    = threadIdx.x;
    const int wave = t >> 6;
    const int lane = t & 63;

    const int rbase = blockIdx.x * 16 + wave;   // rows rbase + 4*i

    int  r[4], b[4], l[4];
    bool ok[4];
    #pragma unroll
    for (int i = 0; i < 4; ++i) {
        r[i]  = rbase + 4 * i;
        b[i]  = r[i] & (BATCH - 1);
        l[i]  = r[i] >> 5;
        ok[i] = l[i] < lengths[b[i]];   // wave-uniform
    }
    if (!ok[0] && !ok[1] && !ok[2] && !ok[3]) return;

    // Phase 1: issue all enc loads (HBM, long latency) for valid rows -- NT
    f32x4 e[4][4];
    #pragma unroll
    for (int i = 0; i < 4; ++i) {
        if (ok[i]) {
            const f32x4* ep = (const f32x4*)(enc + (size_t)r[i] * HID);
            #pragma unroll
            for (int j = 0; j < 4; ++j)
                e[i][j] = __builtin_nontemporal_load(ep + j * 64 + lane);
        }
    }

    // Phase 2: v loads (L2-resident) + dot
    float acc[4] = {0.f, 0.f, 0.f, 0.f};
    #pragma unroll
    for (int i = 0; i < 4; ++i) {
        if (ok[i]) {
            const f32x4* vp = (const f32x4*)(v + (size_t)b[i] * HID);
            #pragma unroll
            for (int j = 0; j < 4; ++j) {
                const f32x4 vv = vp[j * 64 + lane];
                const f32x4 ee = e[i][j];
                acc[i] += ee.x * vv.x + ee.y * vv.y + ee.z * vv.z + ee.w * vv.w;
            }
        }
    }

    // Phase 3: 4 independent shuffle reductions (chain latency amortized)
    #pragma unroll
    for (int off = 32; off > 0; off >>= 1) {
        #pragma unroll
        for (int i = 0; i < 4; ++i) acc[i] += __shfl_down(acc[i], off, 64);
    }

    if (lane == 0) {
        #pragma unroll
        for (int i = 0; i < 4; ++i)
            if (ok[i]) energies[(size_t)b[i] * L_SEQ + l[i]] = acc[i] + c[b[i]];
    }
}

// ---------------------------------------------------------------------------
// Kernel 3: masked softmax per batch row, renormalized over valid positions.
// Invalid l get energy FLOAT_MIN -> exp underflows to exact 0, so plain
// softmax over the masked energies equals the reference's masked/sums.
// energies[l >= len] is never read (it was never written).
// Grid: B blocks, 256 threads, 8 elements/thread.
// ---------------------------------------------------------------------------
__global__ __launch_bounds__(256) void softmax_kernel(
    const float* __restrict__ energies, // [B,L]
    const int*   __restrict__ lengths,  // [B]
    float* __restrict__ out)            // [B,1,L]
{
    __shared__ float red[4];

    const int b   = blockIdx.x;
    const int t   = threadIdx.x;
    const int len = lengths[b];

    float e[8];
    float m = -INFINITY;
    #pragma unroll
    for (int i = 0; i < 8; ++i) {
        const int l = t + i * 256;
        e[i] = (l < len) ? energies[(size_t)b * L_SEQ + l] : FLOAT_MIN;
        m = fmaxf(m, e[i]);
    }
    #pragma unroll
    for (int off = 32; off > 0; off >>= 1) m = fmaxf(m, __shfl_down(m, off, 64));
    if ((t & 63) == 0) red[t >> 6] = m;
    __syncthreads();
    m = fmaxf(fmaxf(red[0], red[1]), fmaxf(red[2], red[3]));
    __syncthreads();   // before reusing red[]

    float p[8];
    float s = 0.f;
    #pragma unroll
    for (int i = 0; i < 8; ++i) {
        p[i] = __expf(e[i] - m);   // FLOAT_MIN rows underflow to exactly 0
        s += p[i];
    }
    #pragma unroll
    for (int off = 32; off > 0; off >>= 1) s += __shfl_down(s, off, 64);
    if ((t & 63) == 0) red[t >> 6] = s;
    __syncthreads();
    s = red[0] + red[1] + red[2] + red[3];

    const float inv = 1.0f / s;
    #pragma unroll
    for (int i = 0; i < 8; ++i) {
        const int l = t + i * 256;
        out[(size_t)b * L_SEQ + l] = p[i] * inv;
    }
}

// ---------------------------------------------------------------------------
extern "C" void kernel_launch(void* const* d_in, const int* in_sizes, int n_in,
                              void* d_out, int out_size, void* d_ws, size_t ws_size,
                              hipStream_t stream) {
    const float* hidden  = (const float*)d_in[0];  // (1,B,H)
    const float* enc     = (const float*)d_in[1];  // (L,B,H)
    const float* W       = (const float*)d_in[2];  // (H,H)
    const float* bias    = (const float*)d_in[3];  // (H,)
    const int*   lengths = (const int*)d_in[4];    // (B,)
    float* out = (float*)d_out;                    // (B,1,L) fp32

    // workspace layout: v[B*H] | c[B] | energies[B*L]   (~393 KB)
    float* v        = (float*)d_ws;
    float* c        = v + BATCH * HID;
    float* energies = c + BATCH;

    proj_kernel   <<<256,                  256, 0, stream>>>(hidden, W, bias, v, c);
    energy_kernel <<<(L_SEQ * BATCH) / 16, 256, 0, stream>>>(enc, v, c, lengths, energies);
    softmax_kernel<<<BATCH,                256, 0, stream>>>(energies, lengths, out);
}